// Round 9
// baseline (1221.249 us; speedup 1.0000x reference)
//
#include <hip/hip_runtime.h>
#include <math.h>

#define Bn 256
#define Cn 3
#define Hn 224
#define Wn 224
#define CROPD 190

static constexpr int PLANE = Hn * Wn;   // 50176

#define TILE 32
// F (source) tile, f32, zero-padded outside image
#define FH 72
#define FSTR 76                  // 76%32=12
// P tile, f32, zero-padded outside image
#define PHR 44
#define PSTR 52                  // 52%32=20 (48 aliased: rows+2 same bank)
// R/T tiles overlay F region
#define RSTR 36                  // 36%32=4  (40 aliased rows+4)

#define NWG (Bn * 49)            // 12,544 blocks; one per (batch,tile), 3 channels each
#define CHUNK (NWG / 8)          // 1568

__device__ int    g_i0[Wn];
__device__ float4 g_wt[Wn];

__device__ __forceinline__ float keys_cubic(float x) {
    if (x < 1.f) return ((1.5f * x - 2.5f) * x) * x + 1.f;
    if (x < 2.f) return ((-0.5f * x + 2.5f) * x - 4.f) * x + 2.f;
    return 0.f;
}
__device__ __forceinline__ float rflf(float v) {
    return __int_as_float(__builtin_amdgcn_readfirstlane(__float_as_int(v)));
}
__device__ __forceinline__ int rfli(int v) { return __builtin_amdgcn_readfirstlane(v); }
__device__ __forceinline__ int swz_block(int bid) {
    return (bid & 7) * CHUNK + (bid >> 3);   // bijective, NWG%8==0
}

// params[b*12 + {0..7: homography, 8: cos, 9: sin, 10: brightness, 11: flip}]
__global__ void params_kernel(const int* __restrict__ ep_raw,
                              const int* __restrict__ angles,
                              const float* __restrict__ brightness,
                              const int* __restrict__ flip_mask,
                              float* __restrict__ params) {
    int b = threadIdx.x;

    if (b < Wn) {
        float sf = ((float)b + 0.5f) * ((float)CROPD / (float)Wn) - 0.5f;
        int i0 = (int)floorf(sf);
        float w[4]; float s = 0.f;
#pragma unroll
        for (int k = 0; k < 4; k++) {
            int idx = i0 - 1 + k;
            float wk = (idx >= 0 && idx < CROPD) ? keys_cubic(fabsf(sf - (float)idx)) : 0.f;
            w[k] = wk; s += wk;
        }
        float inv = 1.f / s;
        g_i0[b] = i0;
        g_wt[b] = make_float4(w[0] * inv, w[1] * inv, w[2] * inv, w[3] * inv);
    }

    if (b >= Bn) return;

    const double offx[4] = {0.0, 195.0, 195.0, 0.0};
    const double offy[4] = {0.0, 0.0, 195.0, 195.0};
    const double sxc[4]  = {0.0, 223.0, 223.0, 0.0};
    const double syc[4]  = {0.0, 0.0, 223.0, 223.0};
    double M[8][9];
    for (int i = 0; i < 4; i++) {
        double ex = (double)ep_raw[b * 8 + i * 2 + 0] + offx[i];
        double ey = (double)ep_raw[b * 8 + i * 2 + 1] + offy[i];
        double sx = sxc[i], sy = syc[i];
        M[i][0] = ex; M[i][1] = ey; M[i][2] = 1.0;
        M[i][3] = 0.0; M[i][4] = 0.0; M[i][5] = 0.0;
        M[i][6] = -sx * ex; M[i][7] = -sx * ey; M[i][8] = sx;
        M[i + 4][0] = 0.0; M[i + 4][1] = 0.0; M[i + 4][2] = 0.0;
        M[i + 4][3] = ex; M[i + 4][4] = ey; M[i + 4][5] = 1.0;
        M[i + 4][6] = -sy * ex; M[i + 4][7] = -sy * ey; M[i + 4][8] = sy;
    }
    for (int k = 0; k < 8; k++) {
        int piv = k; double best = fabs(M[k][k]);
        for (int r = k + 1; r < 8; r++) {
            double v = fabs(M[r][k]);
            if (v > best) { best = v; piv = r; }
        }
        if (piv != k)
            for (int j = 0; j < 9; j++) { double tt = M[k][j]; M[k][j] = M[piv][j]; M[piv][j] = tt; }
        double inv = 1.0 / M[k][k];
        for (int r = k + 1; r < 8; r++) {
            double f = M[r][k] * inv;
            M[r][k] = 0.0;
            for (int j = k + 1; j < 9; j++) M[r][j] -= f * M[k][j];
        }
    }
    double sol[8];
    for (int k = 7; k >= 0; k--) {
        double s = M[k][8];
        for (int j = k + 1; j < 8; j++) s -= M[k][j] * sol[j];
        sol[k] = s / M[k][k];
    }
    float* p = params + b * 12;
    for (int j = 0; j < 8; j++) p[j] = (float)sol[j];
    double th = ((double)angles[b] - 16.0) * (M_PI / 180.0);
    p[8]  = (float)cos(th);
    p[9]  = (float)sin(th);
    p[10] = 0.85f + 0.3f * brightness[b];
    p[11] = (flip_mask[b] > 0) ? 1.0f : 0.0f;
}

// Per-(batch,tile): rmeta = UNCLAMPED rot bbox (P-rect); smeta = UNCLAMPED
// persp source bbox of that P-rect (x0s aligned down to mult of 4).
__global__ void meta_kernel(const float* __restrict__ params,
                            const int* __restrict__ crop_ij,
                            int4* __restrict__ rmeta,
                            int4* __restrict__ smeta) {
    int bt = blockIdx.x * 256 + threadIdx.x;    // < 12544
    int b = bt / 49, t = bt % 49;
    int ty = (t / 7) * TILE, tx = (t % 7) * TILE;
    const float* prm = params + b * 12;

    int x0p, y0p, bwp, bhp;
    {
        float cs = prm[8], sn = prm[9];
        int ci = crop_ij[b * 2 + 0], cj = crop_ij[b * 2 + 1];
        int iymin = max(g_i0[ty] - 1, 0);
        int iymax = min(g_i0[ty + 31] + 2, CROPD - 1);
        int jmin = max(g_i0[tx] - 1, 0);
        int jmax = min(g_i0[tx + 31] + 2, CROPD - 1);
        int ry0 = iymin + ci, ry1 = iymax + ci;
        int rx0 = jmin + cj, rx1 = jmax + cj;
        const float cxc = (Wn - 1) * 0.5f;
        float minrx = 1e30f, maxrx = -1e30f, minry = 1e30f, maxry = -1e30f;
#pragma unroll
        for (int cy = 0; cy < 2; cy++) {
#pragma unroll
            for (int cxr = 0; cxr < 2; cxr++) {
                float dx = (float)(cxr ? rx1 : rx0) - cxc;
                float dy = (float)(cy ? ry1 : ry0) - cxc;
                float rx = cs * dx + sn * dy + cxc;
                float ry = -sn * dx + cs * dy + cxc;
                minrx = fminf(minrx, rx); maxrx = fmaxf(maxrx, rx);
                minry = fminf(minry, ry); maxry = fmaxf(maxry, ry);
            }
        }
        x0p = (int)floorf(minrx) - 1;
        y0p = (int)floorf(minry) - 1;
        bwp = ((int)floorf(maxrx) + 2) - x0p + 1;
        bhp = ((int)floorf(maxry) + 2) - y0p + 1;
        rmeta[bt] = make_int4(x0p, y0p, bwp, bhp);
    }

    {
        float a0 = prm[0], a1 = prm[1], a2 = prm[2];
        float a3 = prm[3], a4 = prm[4], a5 = prm[5];
        float g = prm[6], h = prm[7];
        int x1p = x0p + bwp - 1, y1p = y0p + bhp - 1;
        float minsx = 1e30f, maxsx = -1e30f, minsy = 1e30f, maxsy = -1e30f;
#pragma unroll
        for (int cy = 0; cy < 2; cy++) {
#pragma unroll
            for (int cxr = 0; cxr < 2; cxr++) {
                float Xg = (float)(cxr ? x1p : x0p) + 0.5f;
                float Yg = (float)(cy ? y1p : y0p) + 0.5f;
                float rden = 1.0f / (g * Xg + h * Yg + 1.0f);
                float sx = (a0 * Xg + a1 * Yg + a2) * rden - 0.5f;
                float sy = (a3 * Xg + a4 * Yg + a5) * rden - 0.5f;
                minsx = fminf(minsx, sx); maxsx = fmaxf(maxsx, sx);
                minsy = fminf(minsy, sy); maxsy = fmaxf(maxsy, sy);
            }
        }
        int x0s = ((int)floorf(minsx) - 1) & ~3;         // align (works for negatives)
        int y0s = (int)floorf(minsy) - 1;
        int bws = ((int)floorf(maxsx) + 2) - x0s + 1;
        int bhs = ((int)floorf(maxsy) + 2) - y0s + 1;
        smeta[bt] = make_int4(x0s, y0s, bws, bhs);
    }
}

// On-demand perspective sample with global taps (fallback path only).
__device__ __forceinline__ float persp_at(const float* __restrict__ xb,
                                          const float* __restrict__ nb,
                                          bool flip, float bf,
                                          float a0, float a1, float a2,
                                          float a3, float a4, float a5,
                                          float g, float h, int ixp, int iyp) {
    float Xg = (float)ixp + 0.5f, Yg = (float)iyp + 0.5f;
    float rden = __builtin_amdgcn_rcpf(g * Xg + h * Yg + 1.0f);
    float sx = (a0 * Xg + a1 * Yg + a2) * rden - 0.5f;
    float sy = (a3 * Xg + a4 * Yg + a5) * rden - 0.5f;
    float fx0 = floorf(sx), fy0 = floorf(sy);
    float wx = sx - fx0, wy = sy - fy0;
    int x0 = (int)fx0, y0 = (int)fy0;
    float acc = 0.f;
#pragma unroll
    for (int dy = 0; dy < 2; dy++) {
        int yy = y0 + dy;
        float wyv = dy ? wy : 1.f - wy;
        bool yv = (unsigned)yy < (unsigned)Hn;
        int yc = min(max(yy, 0), Hn - 1);
#pragma unroll
        for (int dx = 0; dx < 2; dx++) {
            int xx = x0 + dx;
            float wxv = dx ? wx : 1.f - wx;
            bool v = yv && ((unsigned)xx < (unsigned)Wn);
            int xc = min(max(xx, 0), Wn - 1);
            float wgt = v ? wxv * wyv : 0.f;
            int xs = flip ? (Wn - 1 - xc) : xc;
            acc += (xb[yc * Wn + xs] + 0.625f * nb[yc * Wn + xc]) * bf * wgt;
        }
    }
    return acc;
}

// One block = one (batch, 32x32 tile) x ALL 3 CHANNELS.
// Coordinates computed ONCE (channel-independent) into registers; the
// channel loop re-runs only the data phases. Zero-padded F/P tiles make
// border handling branch-free (w*valid*v[clamp] == w*Fpad[unclamped]).
// LDS = 72*76*4 + 44*52*4 = 31,040 B; R/T (2x32x36) overlay dead F region.
__global__ __launch_bounds__(256, 4) void mega_kernel(const float* __restrict__ xin,
                                                      const float* __restrict__ noise,
                                                      const float* __restrict__ params,
                                                      const int* __restrict__ crop_ij,
                                                      const int4* __restrict__ rmeta,
                                                      const int4* __restrict__ smeta,
                                                      float* __restrict__ out) {
    __shared__ __align__(16) float smem[FH * FSTR + PHR * PSTR];
    float* Flds = smem;
    float* Plds = smem + FH * FSTR;
    float* Rlds = smem;                      // overlays F (dead after P phase)
    float* Tlds = smem + 32 * RSTR;

    int bt = swz_block(blockIdx.x);          // == b*49 + t
    int b = bt / 49;
    int t = bt - b * 49;
    int ty = (t / 7) * TILE;
    int tx = (t % 7) * TILE;
    int tid = threadIdx.x;

    int4 rm = rmeta[bt];
    int x0p = rm.x, y0p = rm.y, bwp = rm.z, bhp = rm.w;
    int4 sm = smeta[bt];
    int x0s = sm.x, y0s = sm.y, bws = sm.z, bhs = sm.w;
    bool fast = (bws <= FH) && (bhs <= FH) && (bwp <= PHR) && (bhp <= PHR);

    const float* prm = params + b * 12;
    float a0 = rflf(prm[0]), a1 = rflf(prm[1]), a2 = rflf(prm[2]);
    float a3 = rflf(prm[3]), a4 = rflf(prm[4]), a5 = rflf(prm[5]);
    float g = rflf(prm[6]), h = rflf(prm[7]), bf = rflf(prm[10]);
    float cs = rflf(prm[8]), sn = rflf(prm[9]);
    bool flip = rflf(prm[11]) > 0.5f;
    int ci = rfli(crop_ij[b * 2 + 0]);
    int cj = rfli(crop_ij[b * 2 + 1]);

    int iymin = max(g_i0[ty] - 1, 0);
    int nTy = min(g_i0[ty + 31] + 2, CROPD - 1) - iymin + 1;
    int jmin = max(g_i0[tx] - 1, 0);
    int nRx = min(g_i0[tx + 31] + 2, CROPD - 1) - jmin + 1;
    int rx0 = jmin + cj, ry0 = iymin + ci;
    const float cxc = (Wn - 1) * 0.5f;

    // ================= channel-independent coordinate precompute ============
    // --- F staging geometry ---
    int bwq = (bws + 3) >> 2;                          // <= 18
    unsigned Mf = (1u << 20) / (unsigned)bwq + 1;
    int totF = bhs * bwq;                              // <= 1296
    // --- P coords: 2 static elems x 4 pixels; sign bit of off = out-of-image
    int bwpq = (bwp + 3) >> 2;                         // <= 11
    unsigned Mp = (1u << 20) / (unsigned)bwpq + 1;
    int totP = bhp * bwpq;                             // <= 484 (< 512)
    int   poff[2][4]; float pwx[2][4], pwy[2][4];
    int   psto[2];                                     // store offset, -1 invalid
    int x1p = x0p + bwp - 1;
#pragma unroll
    for (int ee = 0; ee < 2; ee++) {
        int e = tid + ee * 256;
        psto[ee] = -1;
        if (e < totP) {
            int pr = (int)(((unsigned)e * Mp) >> 20);
            int pc = e - pr * bwpq;
            psto[ee] = pr * PSTR + pc * 4;
            int py = y0p + pr;
            float Yg = (float)py + 0.5f;
#pragma unroll
            for (int j = 0; j < 4; j++) {
                int px = min(x0p + pc * 4 + j, x1p);   // dup-pad past bwp (never read)
                float Xg = (float)px + 0.5f;
                float r = __builtin_amdgcn_rcpf(g * Xg + h * Yg + 1.0f);
                float sx = (a0 * Xg + a1 * Yg + a2) * r - 0.5f;
                float sy = (a3 * Xg + a4 * Yg + a5) * r - 0.5f;
                float fx = floorf(sx), fy = floorf(sy);
                int ix = (int)fx, iy = (int)fy;
                pwx[ee][j] = sx - fx;
                pwy[ee][j] = sy - fy;
                int off = (iy - y0s) * FSTR + (ix - x0s);
                bool inimg = ((unsigned)px < (unsigned)Wn) & ((unsigned)py < (unsigned)Hn);
                poff[ee][j] = inimg ? off : (off | 0x40000000);  // flag bit (off < 2^14)
            }
        }
    }
    // --- R coords: 4 static elems ---
    int   roff[4], rsto[4]; float rwx[4], rwy[4];
    {
        int rc = tid & 31;
        int rbase = tid >> 5;
        float dxc = (float)(rx0 + rc) - cxc;
        float bx = cs * dxc + cxc;
        float by = -sn * dxc + cxc;
#pragma unroll
        for (int it = 0; it < 4; it++) {
            int rr = it * 8 + rbase;
            rsto[it] = -1;
            if (rr < nTy && rc < nRx) {
                rsto[it] = rr * RSTR + rc;
                float dyr = (float)(ry0 + rr) - cxc;
                float srx = bx + sn * dyr;
                float sry = by + cs * dyr;
                float fx = floorf(srx), fy = floorf(sry);
                rwx[it] = srx - fx;
                rwy[it] = sry - fy;
                roff[it] = ((int)fy - y0p) * PSTR + ((int)fx - x0p);
            }
        }
    }
    // --- T coords ---
    float4 twt; int jc0, jc1, jc2, jc3;
    {
        int oc = tid & 31;
        int ox = tx + oc;
        twt = g_wt[ox];
        int j0 = g_i0[ox];
        jc0 = min(max(j0 - 1, 0), CROPD - 1) - jmin;
        jc1 = min(max(j0 + 0, 0), CROPD - 1) - jmin;
        jc2 = min(max(j0 + 1, 0), CROPD - 1) - jmin;
        jc3 = min(max(j0 + 2, 0), CROPD - 1) - jmin;
    }
    // --- V coords ---
    float4 vwt; int iyc0, iyc1, iyc2, iyc3; int voutoff;
    {
        int r = tid >> 3, cg = tid & 7;
        int oy = ty + r;
        vwt = g_wt[oy];
        int i0y = g_i0[oy];
        iyc0 = (min(max(i0y - 1, 0), CROPD - 1) - iymin) * RSTR + cg * 4;
        iyc1 = (min(max(i0y + 0, 0), CROPD - 1) - iymin) * RSTR + cg * 4;
        iyc2 = (min(max(i0y + 1, 0), CROPD - 1) - iymin) * RSTR + cg * 4;
        iyc3 = (min(max(i0y + 2, 0), CROPD - 1) - iymin) * RSTR + cg * 4;
        voutoff = oy * Wn + tx + cg * 4;
    }

    // ========================== channel loop ================================
    for (int c = 0; c < Cn; c++) {
        const size_t base = ((size_t)b * Cn + c) * (size_t)PLANE;
        const float* xb = xin + base;
        const float* nb = noise + base;

        if (fast) {
            // ---- F: stage zero-padded (flip(x)+0.625*noise)*bf ----
#pragma unroll
            for (int it = 0; it < 6; it++) {
                int e = tid + it * 256;
                if (e < totF) {
                    int fr = (int)(((unsigned)e * Mf) >> 20);
                    int fc = e - fr * bwq;
                    int yy = y0s + fr;
                    int xl = x0s + fc * 4;
                    bool yok = (unsigned)yy < (unsigned)Hn;
                    float4 f;
                    if (yok && xl >= 0 && xl <= Wn - 4) {
                        float4 nv = *reinterpret_cast<const float4*>(&nb[yy * Wn + xl]);
                        float4 xv;
                        if (flip) {
                            float4 xr = *reinterpret_cast<const float4*>(&xb[yy * Wn + (Wn - 4 - xl)]);
                            xv = make_float4(xr.w, xr.z, xr.y, xr.x);
                        } else {
                            xv = *reinterpret_cast<const float4*>(&xb[yy * Wn + xl]);
                        }
                        f = make_float4((xv.x + 0.625f * nv.x) * bf,
                                        (xv.y + 0.625f * nv.y) * bf,
                                        (xv.z + 0.625f * nv.z) * bf,
                                        (xv.w + 0.625f * nv.w) * bf);
                    } else {
                        float v[4];
#pragma unroll
                        for (int j = 0; j < 4; j++) {
                            int xj = xl + j;
                            bool ok = yok && ((unsigned)xj < (unsigned)Wn);
                            int xs = flip ? (Wn - 1 - xj) : xj;
                            v[j] = ok ? (xb[yy * Wn + xs] + 0.625f * nb[yy * Wn + xj]) * bf
                                      : 0.f;
                        }
                        f = make_float4(v[0], v[1], v[2], v[3]);
                    }
                    *reinterpret_cast<float4*>(&Flds[fr * FSTR + fc * 4]) = f;
                }
            }
            __syncthreads();

            // ---- P: uniform lerp taps via stored coords ----
#pragma unroll
            for (int ee = 0; ee < 2; ee++) {
                if (psto[ee] >= 0) {
                    float pv[4];
#pragma unroll
                    for (int j = 0; j < 4; j++) {
                        int o = poff[ee][j];
                        const float* q = &Flds[o & 0x3fffffff];
                        float wx = pwx[ee][j], wy = pwy[ee][j];
                        float top = q[0] + wx * (q[1] - q[0]);
                        float bot = q[FSTR] + wx * (q[FSTR + 1] - q[FSTR]);
                        float v = top + wy * (bot - top);
                        pv[j] = (o & 0x40000000) ? 0.f : v;
                    }
                    *reinterpret_cast<float4*>(&Plds[psto[ee]]) =
                        make_float4(pv[0], pv[1], pv[2], pv[3]);
                }
            }
            __syncthreads();

            // ---- R: uniform lerp taps via stored coords ----
#pragma unroll
            for (int it = 0; it < 4; it++) {
                if (rsto[it] >= 0) {
                    const float* q = &Plds[roff[it]];
                    float wx = rwx[it], wy = rwy[it];
                    float top = q[0] + wx * (q[1] - q[0]);
                    float bot = q[PSTR] + wx * (q[PSTR + 1] - q[PSTR]);
                    Rlds[rsto[it]] = top + wy * (bot - top);
                }
            }
        } else {
            // ---- rare fallback: direct global-tap R (exact semantics) ----
            __syncthreads();        // match F barrier
            __syncthreads();        // match P barrier
            int rc = tid & 31;
            int rbase = tid >> 5;
            float dxc = (float)(rx0 + rc) - cxc;
            float bx = cs * dxc + cxc;
            float by = -sn * dxc + cxc;
#pragma unroll
            for (int it = 0; it < 4; it++) {
                int rr = it * 8 + rbase;
                if (rr < nTy && rc < nRx) {
                    float dyr = (float)(ry0 + rr) - cxc;
                    float srx = bx + sn * dyr;
                    float sry = by + cs * dyr;
                    float fx0 = floorf(srx), fy0 = floorf(sry);
                    float wx = srx - fx0, wy = sry - fy0;
                    int x0 = (int)fx0, y0 = (int)fy0;
                    float acc = 0.f;
#pragma unroll
                    for (int ddy = 0; ddy < 2; ddy++) {
                        int yy = y0 + ddy;
                        float wyv = ddy ? wy : 1.f - wy;
                        bool yv = (unsigned)yy < (unsigned)Hn;
                        int yc = min(max(yy, 0), Hn - 1);
#pragma unroll
                        for (int ddx = 0; ddx < 2; ddx++) {
                            int xx = x0 + ddx;
                            float wxv = ddx ? wx : 1.f - wx;
                            bool v = yv && ((unsigned)xx < (unsigned)Wn);
                            int xc = min(max(xx, 0), Wn - 1);
                            float wgt = v ? wxv * wyv : 0.f;
                            if (wgt != 0.f)
                                acc += persp_at(xb, nb, flip, bf, a0, a1, a2,
                                                a3, a4, a5, g, h, xc, yc) * wgt;
                        }
                    }
                    Rlds[rr * RSTR + rc] = acc;
                }
            }
        }
        __syncthreads();

        // ---- T: horizontal bicubic ----
        {
            int rbase = tid >> 5;
            int oc = tid & 31;
#pragma unroll
            for (int it = 0; it < 4; it++) {
                int rr = it * 8 + rbase;
                if (rr < nTy) {
                    const float* row = &Rlds[rr * RSTR];
                    Tlds[rr * RSTR + oc] = twt.x * row[jc0] + twt.y * row[jc1] +
                                           twt.z * row[jc2] + twt.w * row[jc3];
                }
            }
        }
        __syncthreads();

        // ---- V: vertical bicubic, float4 store ----
        {
            float4 v0 = *reinterpret_cast<const float4*>(&Tlds[iyc0]);
            float4 v1 = *reinterpret_cast<const float4*>(&Tlds[iyc1]);
            float4 v2 = *reinterpret_cast<const float4*>(&Tlds[iyc2]);
            float4 v3 = *reinterpret_cast<const float4*>(&Tlds[iyc3]);
            float4 acc;
            acc.x = vwt.x * v0.x + vwt.y * v1.x + vwt.z * v2.x + vwt.w * v3.x;
            acc.y = vwt.x * v0.y + vwt.y * v1.y + vwt.z * v2.y + vwt.w * v3.y;
            acc.z = vwt.x * v0.z + vwt.y * v1.z + vwt.z * v2.z + vwt.w * v3.z;
            acc.w = vwt.x * v0.w + vwt.y * v1.w + vwt.z * v2.w + vwt.w * v3.w;
            *reinterpret_cast<float4*>(out + base + voutoff) = acc;
        }
        __syncthreads();   // R/T (overlaying F) must be free before next F stage
    }
}

extern "C" void kernel_launch(void* const* d_in, const int* in_sizes, int n_in,
                              void* d_out, int out_size, void* d_ws, size_t ws_size,
                              hipStream_t stream) {
    const float* x          = (const float*)d_in[0];
    const float* noise      = (const float*)d_in[1];
    const float* brightness = (const float*)d_in[2];
    const int*   flip_mask  = (const int*)d_in[3];
    const int*   ep_raw     = (const int*)d_in[4];
    const int*   angles     = (const int*)d_in[5];
    const int*   crop_ij    = (const int*)d_in[6];
    float* out = (float*)d_out;

    float* params = (float*)d_ws;                              // 12 KB
    int4*  rmeta  = (int4*)((char*)d_ws + 16384);              // 12544*16
    int4*  smeta  = (int4*)((char*)d_ws + 16384 + 200704);

    params_kernel<<<1, 256, 0, stream>>>(ep_raw, angles, brightness, flip_mask, params);
    meta_kernel<<<49, 256, 0, stream>>>(params, crop_ij, rmeta, smeta);
    mega_kernel<<<NWG, 256, 0, stream>>>(x, noise, params, crop_ij, rmeta, smeta, out);
}

// Round 10
// 261.299 us; speedup vs baseline: 4.6738x; 4.6738x over previous
//
#include <hip/hip_runtime.h>
#include <math.h>

#define Bn 256
#define Cn 3
#define Hn 224
#define Wn 224
#define CROPD 190

static constexpr int PLANE = Hn * Wn;   // 50176

#define TILE 32
// F (source) tile, f32, ZERO-PADDED outside image (unclamped bbox)
#define FH 72
#define FSTR 76                  // 76%32=12
// P tile, f32, zero-padded outside image (unclamped rot bbox)
#define PHR 44
#define PSTR 52                  // 52%32=20 (48 aliased rows+2)
// R/T tiles overlay F region
#define RSTR 36                  // 36%32=4  (40 aliased rows+4)

#define NWG (768 * 49)           // one block per (plane, tile)
#define CHUNK (NWG / 8)

__device__ int    g_i0[Wn];
__device__ float4 g_wt[Wn];

__device__ __forceinline__ float keys_cubic(float x) {
    if (x < 1.f) return ((1.5f * x - 2.5f) * x) * x + 1.f;
    if (x < 2.f) return ((-0.5f * x + 2.5f) * x - 4.f) * x + 2.f;
    return 0.f;
}
__device__ __forceinline__ float rflf(float v) {
    return __int_as_float(__builtin_amdgcn_readfirstlane(__float_as_int(v)));
}
__device__ __forceinline__ int rfli(int v) { return __builtin_amdgcn_readfirstlane(v); }
__device__ __forceinline__ int swz_block(int bid) {
    return (bid & 7) * CHUNK + (bid >> 3);
}

// params[b*12 + {0..7: homography, 8: cos, 9: sin, 10: brightness, 11: flip}]
__global__ void params_kernel(const int* __restrict__ ep_raw,
                              const int* __restrict__ angles,
                              const float* __restrict__ brightness,
                              const int* __restrict__ flip_mask,
                              float* __restrict__ params) {
    int b = threadIdx.x;

    if (b < Wn) {
        float sf = ((float)b + 0.5f) * ((float)CROPD / (float)Wn) - 0.5f;
        int i0 = (int)floorf(sf);
        float w[4]; float s = 0.f;
#pragma unroll
        for (int k = 0; k < 4; k++) {
            int idx = i0 - 1 + k;
            float wk = (idx >= 0 && idx < CROPD) ? keys_cubic(fabsf(sf - (float)idx)) : 0.f;
            w[k] = wk; s += wk;
        }
        float inv = 1.f / s;
        g_i0[b] = i0;
        g_wt[b] = make_float4(w[0] * inv, w[1] * inv, w[2] * inv, w[3] * inv);
    }

    if (b >= Bn) return;

    const double offx[4] = {0.0, 195.0, 195.0, 0.0};
    const double offy[4] = {0.0, 0.0, 195.0, 195.0};
    const double sxc[4]  = {0.0, 223.0, 223.0, 0.0};
    const double syc[4]  = {0.0, 0.0, 223.0, 223.0};
    double M[8][9];
    for (int i = 0; i < 4; i++) {
        double ex = (double)ep_raw[b * 8 + i * 2 + 0] + offx[i];
        double ey = (double)ep_raw[b * 8 + i * 2 + 1] + offy[i];
        double sx = sxc[i], sy = syc[i];
        M[i][0] = ex; M[i][1] = ey; M[i][2] = 1.0;
        M[i][3] = 0.0; M[i][4] = 0.0; M[i][5] = 0.0;
        M[i][6] = -sx * ex; M[i][7] = -sx * ey; M[i][8] = sx;
        M[i + 4][0] = 0.0; M[i + 4][1] = 0.0; M[i + 4][2] = 0.0;
        M[i + 4][3] = ex; M[i + 4][4] = ey; M[i + 4][5] = 1.0;
        M[i + 4][6] = -sy * ex; M[i + 4][7] = -sy * ey; M[i + 4][8] = sy;
    }
    for (int k = 0; k < 8; k++) {
        int piv = k; double best = fabs(M[k][k]);
        for (int r = k + 1; r < 8; r++) {
            double v = fabs(M[r][k]);
            if (v > best) { best = v; piv = r; }
        }
        if (piv != k)
            for (int j = 0; j < 9; j++) { double tt = M[k][j]; M[k][j] = M[piv][j]; M[piv][j] = tt; }
        double inv = 1.0 / M[k][k];
        for (int r = k + 1; r < 8; r++) {
            double f = M[r][k] * inv;
            M[r][k] = 0.0;
            for (int j = k + 1; j < 9; j++) M[r][j] -= f * M[k][j];
        }
    }
    double sol[8];
    for (int k = 7; k >= 0; k--) {
        double s = M[k][8];
        for (int j = k + 1; j < 8; j++) s -= M[k][j] * sol[j];
        sol[k] = s / M[k][k];
    }
    float* p = params + b * 12;
    for (int j = 0; j < 8; j++) p[j] = (float)sol[j];
    double th = ((double)angles[b] - 16.0) * (M_PI / 180.0);
    p[8]  = (float)cos(th);
    p[9]  = (float)sin(th);
    p[10] = 0.85f + 0.3f * brightness[b];
    p[11] = (flip_mask[b] > 0) ? 1.0f : 0.0f;
}

// Per-(batch,tile): rmeta = UNCLAMPED rot bbox (P-rect); smeta = UNCLAMPED
// persp source bbox of that P-rect (x0s aligned down to mult of 4).
__global__ void meta_kernel(const float* __restrict__ params,
                            const int* __restrict__ crop_ij,
                            int4* __restrict__ rmeta,
                            int4* __restrict__ smeta) {
    int bt = blockIdx.x * 256 + threadIdx.x;    // < 12544
    int b = bt / 49, t = bt % 49;
    int ty = (t / 7) * TILE, tx = (t % 7) * TILE;
    const float* prm = params + b * 12;

    int x0p, y0p, bwp, bhp;
    {
        float cs = prm[8], sn = prm[9];
        int ci = crop_ij[b * 2 + 0], cj = crop_ij[b * 2 + 1];
        int iymin = max(g_i0[ty] - 1, 0);
        int iymax = min(g_i0[ty + 31] + 2, CROPD - 1);
        int jmin = max(g_i0[tx] - 1, 0);
        int jmax = min(g_i0[tx + 31] + 2, CROPD - 1);
        int ry0 = iymin + ci, ry1 = iymax + ci;
        int rx0 = jmin + cj, rx1 = jmax + cj;
        const float cxc = (Wn - 1) * 0.5f;
        float minrx = 1e30f, maxrx = -1e30f, minry = 1e30f, maxry = -1e30f;
#pragma unroll
        for (int cy = 0; cy < 2; cy++) {
#pragma unroll
            for (int cxr = 0; cxr < 2; cxr++) {
                float dx = (float)(cxr ? rx1 : rx0) - cxc;
                float dy = (float)(cy ? ry1 : ry0) - cxc;
                float rx = cs * dx + sn * dy + cxc;
                float ry = -sn * dx + cs * dy + cxc;
                minrx = fminf(minrx, rx); maxrx = fmaxf(maxrx, rx);
                minry = fminf(minry, ry); maxry = fmaxf(maxry, ry);
            }
        }
        x0p = (int)floorf(minrx) - 1;
        y0p = (int)floorf(minry) - 1;
        bwp = ((int)floorf(maxrx) + 2) - x0p + 1;
        bhp = ((int)floorf(maxry) + 2) - y0p + 1;
        rmeta[bt] = make_int4(x0p, y0p, bwp, bhp);
    }

    {
        float a0 = prm[0], a1 = prm[1], a2 = prm[2];
        float a3 = prm[3], a4 = prm[4], a5 = prm[5];
        float g = prm[6], h = prm[7];
        int x1p = x0p + bwp - 1, y1p = y0p + bhp - 1;
        float minsx = 1e30f, maxsx = -1e30f, minsy = 1e30f, maxsy = -1e30f;
#pragma unroll
        for (int cy = 0; cy < 2; cy++) {
#pragma unroll
            for (int cxr = 0; cxr < 2; cxr++) {
                float Xg = (float)(cxr ? x1p : x0p) + 0.5f;
                float Yg = (float)(cy ? y1p : y0p) + 0.5f;
                float rden = 1.0f / (g * Xg + h * Yg + 1.0f);
                float sx = (a0 * Xg + a1 * Yg + a2) * rden - 0.5f;
                float sy = (a3 * Xg + a4 * Yg + a5) * rden - 0.5f;
                minsx = fminf(minsx, sx); maxsx = fmaxf(maxsx, sx);
                minsy = fminf(minsy, sy); maxsy = fmaxf(maxsy, sy);
            }
        }
        int x0s = ((int)floorf(minsx) - 1) & ~3;       // align down (ok for negatives)
        int y0s = (int)floorf(minsy) - 1;
        int bws = ((int)floorf(maxsx) + 2) - x0s + 1;
        int bhs = ((int)floorf(maxsy) + 2) - y0s + 1;
        smeta[bt] = make_int4(x0s, y0s, bws, bhs);
    }
}

// On-demand perspective sample with global taps (fallback path only).
__device__ __forceinline__ float persp_at(const float* __restrict__ xb,
                                          const float* __restrict__ nb,
                                          bool flip, float bf,
                                          float a0, float a1, float a2,
                                          float a3, float a4, float a5,
                                          float g, float h, int ixp, int iyp) {
    float Xg = (float)ixp + 0.5f, Yg = (float)iyp + 0.5f;
    float rden = __builtin_amdgcn_rcpf(g * Xg + h * Yg + 1.0f);
    float sx = (a0 * Xg + a1 * Yg + a2) * rden - 0.5f;
    float sy = (a3 * Xg + a4 * Yg + a5) * rden - 0.5f;
    float fx0 = floorf(sx), fy0 = floorf(sy);
    float wx = sx - fx0, wy = sy - fy0;
    int x0 = (int)fx0, y0 = (int)fy0;
    float acc = 0.f;
#pragma unroll
    for (int dy = 0; dy < 2; dy++) {
        int yy = y0 + dy;
        float wyv = dy ? wy : 1.f - wy;
        bool yv = (unsigned)yy < (unsigned)Hn;
        int yc = min(max(yy, 0), Hn - 1);
#pragma unroll
        for (int dx = 0; dx < 2; dx++) {
            int xx = x0 + dx;
            float wxv = dx ? wx : 1.f - wx;
            bool v = yv && ((unsigned)xx < (unsigned)Wn);
            int xc = min(max(xx, 0), Wn - 1);
            float wgt = v ? wxv * wyv : 0.f;
            int xs = flip ? (Wn - 1 - xc) : xc;
            acc += (xb[yc * Wn + xs] + 0.625f * nb[yc * Wn + xc]) * bf * wgt;
        }
    }
    return acc;
}

// Fully fused pipeline, one (plane,tile) per block. Zero-padded F/P tiles
// make every phase a single uniform lerp path (no border branches).
// All coords computed inline per phase — NO register arrays across barriers
// (R9's channel-shared coord cache spilled to scratch: 5.5 GB writes).
// LDS = 72*76*4 + 44*52*4 = 31,040 B -> 5 blocks/CU (LDS-limited).
__global__ __launch_bounds__(256, 4) void mega_kernel(const float* __restrict__ xin,
                                                      const float* __restrict__ noise,
                                                      const float* __restrict__ params,
                                                      const int* __restrict__ crop_ij,
                                                      const int4* __restrict__ rmeta,
                                                      const int4* __restrict__ smeta,
                                                      float* __restrict__ out) {
    __shared__ __align__(16) float smem[FH * FSTR + PHR * PSTR];
    float* Flds = smem;
    float* Plds = smem + FH * FSTR;
    float* Rlds = smem;                      // overlays F (dead after P phase)
    float* Tlds = smem + 32 * RSTR;

    int bi = swz_block(blockIdx.x);
    int p = bi / 49;
    int t = bi % 49;
    int ty = (t / 7) * TILE;
    int tx = (t % 7) * TILE;
    int b = p / Cn;
    int tid = threadIdx.x;
    int bt = b * 49 + t;

    int4 rm = rmeta[bt];
    int x0p = rm.x, y0p = rm.y, bwp = rm.z, bhp = rm.w;
    int4 sm = smeta[bt];
    int x0s = sm.x, y0s = sm.y, bws = sm.z, bhs = sm.w;
    bool fast = (bws <= FH) && (bhs <= FH) && (bwp <= PHR) && (bhp <= PHR);

    const float* prm = params + b * 12;
    float a0 = rflf(prm[0]), a1 = rflf(prm[1]), a2 = rflf(prm[2]);
    float a3 = rflf(prm[3]), a4 = rflf(prm[4]), a5 = rflf(prm[5]);
    float g = rflf(prm[6]), h = rflf(prm[7]), bf = rflf(prm[10]);
    float cs = rflf(prm[8]), sn = rflf(prm[9]);
    bool flip = rflf(prm[11]) > 0.5f;
    int ci = rfli(crop_ij[b * 2 + 0]);
    int cj = rfli(crop_ij[b * 2 + 1]);

    int iymin = max(g_i0[ty] - 1, 0);
    int nTy = min(g_i0[ty + 31] + 2, CROPD - 1) - iymin + 1;
    int jmin = max(g_i0[tx] - 1, 0);
    int nRx = min(g_i0[tx + 31] + 2, CROPD - 1) - jmin + 1;
    int rx0 = jmin + cj, ry0 = iymin + ci;
    const float cxc = (Wn - 1) * 0.5f;

    const size_t base = (size_t)p * PLANE;
    const float* xb = xin + base;
    const float* nb = noise + base;

    if (fast) {
        // ---- Phase F: zero-padded (flip(x)+0.625*noise)*bf, f32 ----
        {
            int bwq = (bws + 3) >> 2;                     // <= 18
            unsigned Mf = (1u << 20) / (unsigned)bwq + 1;
            int totF = bhs * bwq;                         // <= 1296
            for (int e = tid; e < totF; e += 256) {
                int fr = (int)(((unsigned)e * Mf) >> 20);
                int fc = e - fr * bwq;
                int yy = y0s + fr;
                int xl = x0s + fc * 4;
                bool yok = (unsigned)yy < (unsigned)Hn;
                float4 f;
                if (yok && xl >= 0 && xl <= Wn - 4) {
                    float4 nv = *reinterpret_cast<const float4*>(&nb[yy * Wn + xl]);
                    float4 xv;
                    if (flip) {
                        float4 xr = *reinterpret_cast<const float4*>(&xb[yy * Wn + (Wn - 4 - xl)]);
                        xv = make_float4(xr.w, xr.z, xr.y, xr.x);
                    } else {
                        xv = *reinterpret_cast<const float4*>(&xb[yy * Wn + xl]);
                    }
                    f = make_float4((xv.x + 0.625f * nv.x) * bf,
                                    (xv.y + 0.625f * nv.y) * bf,
                                    (xv.z + 0.625f * nv.z) * bf,
                                    (xv.w + 0.625f * nv.w) * bf);
                } else {
                    float v[4];
#pragma unroll
                    for (int j = 0; j < 4; j++) {
                        int xj = xl + j;
                        bool ok = yok && ((unsigned)xj < (unsigned)Wn);
                        int xs = flip ? (Wn - 1 - xj) : xj;
                        int xcl = min(max(xj, 0), Wn - 1);
                        int xsl = flip ? (Wn - 1 - xcl) : xcl;
                        v[j] = ok ? (xb[yy * Wn + xsl] + 0.625f * nb[yy * Wn + xcl]) * bf
                                  : 0.f;
                        (void)xs;
                    }
                    f = make_float4(v[0], v[1], v[2], v[3]);
                }
                *reinterpret_cast<float4*>(&Flds[fr * FSTR + fc * 4]) = f;
            }
        }
        __syncthreads();

        // ---- Phase P: uniform lerp + in-image select -> zero-padded Plds ----
        {
            int bwpq = (bwp + 3) >> 2;                    // <= 11
            unsigned Mp = (1u << 20) / (unsigned)bwpq + 1;
            int totP = bhp * bwpq;
            int x1p = x0p + bwp - 1;
            for (int e = tid; e < totP; e += 256) {
                int pr = (int)(((unsigned)e * Mp) >> 20);
                int pc = e - pr * bwpq;
                int py = y0p + pr;
                bool yok = (unsigned)py < (unsigned)Hn;
                float Yg = (float)py + 0.5f;
                float pv[4];
#pragma unroll
                for (int j = 0; j < 4; j++) {
                    int px = min(x0p + pc * 4 + j, x1p);  // dup-pad past bwp (never read)
                    float Xg = (float)px + 0.5f;
                    float r = __builtin_amdgcn_rcpf(g * Xg + h * Yg + 1.0f);
                    float sx = (a0 * Xg + a1 * Yg + a2) * r - 0.5f;
                    float sy = (a3 * Xg + a4 * Yg + a5) * r - 0.5f;
                    float fx = floorf(sx), fy = floorf(sy);
                    float wx = sx - fx, wy = sy - fy;
                    const float* q = &Flds[((int)fy - y0s) * FSTR + ((int)fx - x0s)];
                    float top = q[0] + wx * (q[1] - q[0]);
                    float bot = q[FSTR] + wx * (q[FSTR + 1] - q[FSTR]);
                    float v = top + wy * (bot - top);
                    bool inimg = yok && ((unsigned)px < (unsigned)Wn);
                    pv[j] = inimg ? v : 0.f;
                }
                *reinterpret_cast<float4*>(&Plds[pr * PSTR + pc * 4]) =
                    make_float4(pv[0], pv[1], pv[2], pv[3]);
            }
        }
        __syncthreads();

        // ---- Phase R: uniform lerp over zero-padded P ----
        {
            int rc = tid & 31;
            int rbase = tid >> 5;
            bool cok = rc < nRx;
            float dxc = (float)(rx0 + rc) - cxc;
            float bx = cs * dxc + cxc;
            float by = -sn * dxc + cxc;
#pragma unroll
            for (int it = 0; it < 4; it++) {
                int rr = it * 8 + rbase;
                if (rr < nTy && cok) {
                    float dyr = (float)(ry0 + rr) - cxc;
                    float srx = bx + sn * dyr;
                    float sry = by + cs * dyr;
                    float fx = floorf(srx), fy = floorf(sry);
                    float wx = srx - fx, wy = sry - fy;
                    const float* q = &Plds[((int)fy - y0p) * PSTR + ((int)fx - x0p)];
                    float top = q[0] + wx * (q[1] - q[0]);
                    float bot = q[PSTR] + wx * (q[PSTR + 1] - q[PSTR]);
                    Rlds[rr * RSTR + rc] = top + wy * (bot - top);
                }
            }
        }
    } else {
        // ---- rare fallback: direct global-tap R (exact semantics) ----
        int rc = tid & 31;
        int rbase = tid >> 5;
        float dxc = (float)(rx0 + rc) - cxc;
        float bx = cs * dxc + cxc;
        float by = -sn * dxc + cxc;
#pragma unroll
        for (int it = 0; it < 4; it++) {
            int rr = it * 8 + rbase;
            if (rr < nTy && rc < nRx) {
                float dyr = (float)(ry0 + rr) - cxc;
                float srx = bx + sn * dyr;
                float sry = by + cs * dyr;
                float fx0 = floorf(srx), fy0 = floorf(sry);
                float wx = srx - fx0, wy = sry - fy0;
                int x0 = (int)fx0, y0 = (int)fy0;
                float acc = 0.f;
#pragma unroll
                for (int ddy = 0; ddy < 2; ddy++) {
                    int yy = y0 + ddy;
                    float wyv = ddy ? wy : 1.f - wy;
                    bool yv = (unsigned)yy < (unsigned)Hn;
                    int yc = min(max(yy, 0), Hn - 1);
#pragma unroll
                    for (int ddx = 0; ddx < 2; ddx++) {
                        int xx = x0 + ddx;
                        float wxv = ddx ? wx : 1.f - wx;
                        bool v = yv && ((unsigned)xx < (unsigned)Wn);
                        int xc = min(max(xx, 0), Wn - 1);
                        float wgt = v ? wxv * wyv : 0.f;
                        if (wgt != 0.f)
                            acc += persp_at(xb, nb, flip, bf, a0, a1, a2,
                                            a3, a4, a5, g, h, xc, yc) * wgt;
                    }
                }
                Rlds[rr * RSTR + rc] = acc;
            }
        }
    }
    __syncthreads();

    // ---- Phase T: horizontal bicubic ----
    {
        int oc = tid & 31;
        int rbase = tid >> 5;
        int ox = tx + oc;
        float4 w = g_wt[ox];
        int j0 = g_i0[ox];
        int jc0 = min(max(j0 - 1, 0), CROPD - 1) - jmin;
        int jc1 = min(max(j0 + 0, 0), CROPD - 1) - jmin;
        int jc2 = min(max(j0 + 1, 0), CROPD - 1) - jmin;
        int jc3 = min(max(j0 + 2, 0), CROPD - 1) - jmin;
#pragma unroll
        for (int it = 0; it < 4; it++) {
            int rr = it * 8 + rbase;
            if (rr < nTy) {
                const float* row = &Rlds[rr * RSTR];
                Tlds[rr * RSTR + oc] = w.x * row[jc0] + w.y * row[jc1] +
                                       w.z * row[jc2] + w.w * row[jc3];
            }
        }
    }
    __syncthreads();

    // ---- Phase V: vertical bicubic, float4 store ----
    {
        int r = tid >> 3, cg = tid & 7;
        int oy = ty + r, ox0 = tx + cg * 4;
        float4 w = g_wt[oy];
        int i0y = g_i0[oy];
        int iyc0 = (min(max(i0y - 1, 0), CROPD - 1) - iymin) * RSTR + cg * 4;
        int iyc1 = (min(max(i0y + 0, 0), CROPD - 1) - iymin) * RSTR + cg * 4;
        int iyc2 = (min(max(i0y + 1, 0), CROPD - 1) - iymin) * RSTR + cg * 4;
        int iyc3 = (min(max(i0y + 2, 0), CROPD - 1) - iymin) * RSTR + cg * 4;
        float4 v0 = *reinterpret_cast<const float4*>(&Tlds[iyc0]);
        float4 v1 = *reinterpret_cast<const float4*>(&Tlds[iyc1]);
        float4 v2 = *reinterpret_cast<const float4*>(&Tlds[iyc2]);
        float4 v3 = *reinterpret_cast<const float4*>(&Tlds[iyc3]);
        float4 acc;
        acc.x = w.x * v0.x + w.y * v1.x + w.z * v2.x + w.w * v3.x;
        acc.y = w.x * v0.y + w.y * v1.y + w.z * v2.y + w.w * v3.y;
        acc.z = w.x * v0.z + w.y * v1.z + w.z * v2.z + w.w * v3.z;
        acc.w = w.x * v0.w + w.y * v1.w + w.z * v2.w + w.w * v3.w;
        *reinterpret_cast<float4*>(out + base + (size_t)oy * Wn + ox0) = acc;
    }
}

extern "C" void kernel_launch(void* const* d_in, const int* in_sizes, int n_in,
                              void* d_out, int out_size, void* d_ws, size_t ws_size,
                              hipStream_t stream) {
    const float* x          = (const float*)d_in[0];
    const float* noise      = (const float*)d_in[1];
    const float* brightness = (const float*)d_in[2];
    const int*   flip_mask  = (const int*)d_in[3];
    const int*   ep_raw     = (const int*)d_in[4];
    const int*   angles     = (const int*)d_in[5];
    const int*   crop_ij    = (const int*)d_in[6];
    float* out = (float*)d_out;

    float* params = (float*)d_ws;                              // 12 KB
    int4*  rmeta  = (int4*)((char*)d_ws + 16384);              // 12544*16
    int4*  smeta  = (int4*)((char*)d_ws + 16384 + 200704);

    params_kernel<<<1, 256, 0, stream>>>(ep_raw, angles, brightness, flip_mask, params);
    meta_kernel<<<49, 256, 0, stream>>>(params, crop_ij, rmeta, smeta);
    mega_kernel<<<NWG, 256, 0, stream>>>(x, noise, params, crop_ij, rmeta, smeta, out);
}